// Round 5
// baseline (917.072 us; speedup 1.0000x reference)
//
#include <hip/hip_runtime.h>
#include <cstddef>

// RSABlock: conv_offset_mask (3x3) -> DCNv2 -> leaky_relu -> conv3x3 -> +x.
// B=2, C=32, H=W=256, DG=8, K=9, om channels = 216.
//
// Structure:
//   0) transpose_weights: repack w_off/w_c1 -> [chunk][ic*9][8] and
//      w_dcn -> [ic*9][32] so conv weight reads are contiguous wave-uniform
//      (compiler emits s_load; FMA takes SGPR operand).
//   1) conv3x3_tiled<false>: 16x16 pixel tile staged in LDS (32ch, 18x18 halo,
//      41.4KB), grid.z = oc-chunk of 8. Writes om stripe.
//   2) dcn_kernel: per-pixel bilinear gather + contraction, weights via
//      uniform global reads. Writes fea (+bias, leaky relu).
//   3) conv3x3_tiled<true>: same tiling, OC=32, fused residual -> out.
//
// ws layout: fea [2,32,256,256] f32 | wt_off 62208 f | wt_c1 9216 f |
//            wt_dcn 9216 f | om stripe [216][rows][256] f32 (rows%16==0).

#define CH 32
#define DGROUPS 8
#define KK 9
#define CPG (CH / DGROUPS)      // 4
#define OMC (3 * DGROUPS * KK)  // 216
#define NEG_SLOPE 0.2f

#define HH 256
#define WW 256
#define BB 2
#define HW (HH * WW)

#define WOFF_N (OMC * CH * 9)   // 62208
#define WC1_N  (CH * CH * 9)    // 9216
#define WDCN_N (CH * CH * 9)    // 9216

// ---------------------------------------------------------------------------
// Weight repack (runs every call; ws is re-poisoned by the harness).
//   wt_off[c][j][o] = w_off[(c*8+o)*288 + j]   c<27, j<288, o<8
//   wt_c1 [c][j][o] = w_c1 [(c*8+o)*288 + j]   c<4
//   wt_dcn[j][o]    = w_dcn[o*288 + j]         o<32
// ---------------------------------------------------------------------------
__global__ __launch_bounds__(256) void transpose_weights(
    const float* __restrict__ w_off, const float* __restrict__ w_c1,
    const float* __restrict__ w_dcn,
    float* __restrict__ wt_off, float* __restrict__ wt_c1,
    float* __restrict__ wt_dcn)
{
    const int i = blockIdx.x * 256 + threadIdx.x;
    if (i < WOFF_N) {
        const int o = i & 7, j = (i >> 3) % 288, c = (i >> 3) / 288;
        wt_off[i] = w_off[(size_t)(c * 8 + o) * 288 + j];
    } else if (i < WOFF_N + WC1_N) {
        const int t = i - WOFF_N;
        const int o = t & 7, j = (t >> 3) % 288, c = (t >> 3) / 288;
        wt_c1[t] = w_c1[(size_t)(c * 8 + o) * 288 + j];
    } else if (i < WOFF_N + WC1_N + WDCN_N) {
        const int t = i - (WOFF_N + WC1_N);
        const int o = t & 31, j = t >> 5;
        wt_dcn[t] = w_dcn[(size_t)o * 288 + j];
    }
}

// ---------------------------------------------------------------------------
// Tiled 3x3 conv, pad=1, IC=32. Block=256 (16x16 tile); grid=(16, rows/16,
// OC/8). Stages [32][18][18] input tile in LDS, computes 8 output channels
// per thread with weights from wt (contiguous 8 floats per (ic,k): uniform
// s_load_dwordx8). RESID fuses the residual add (global row indexing).
// Output plane layout: [OC][out_rows][WW], rows offset by row_start.
// ---------------------------------------------------------------------------
template <bool RESID>
__global__ __launch_bounds__(256) void conv3x3_tiled(
    const float* __restrict__ in,    // [32, H, W]  (batch base)
    const float* __restrict__ wt,    // [OC/8][288][8]
    const float* __restrict__ bias,  // [OC]
    const float* __restrict__ resid, // [32, H, W] or nullptr
    float* __restrict__ out,         // [OC][out_rows][WW]
    int row_start, int out_rows)
{
    __shared__ float tile[CH * 324];  // 32 x 18 x 18 = 41472 B

    const int tx = threadIdx.x & 15;
    const int ty = threadIdx.x >> 4;
    const int h0 = row_start + blockIdx.y * 16 - 1;  // tile origin (with halo)
    const int w0 = blockIdx.x * 16 - 1;

    for (int idx = threadIdx.x; idx < CH * 324; idx += 256) {
        const int ic  = idx / 324;
        const int rem = idx - ic * 324;
        const int r   = rem / 18;
        const int c   = rem - r * 18;
        const int gy  = h0 + r;
        const int gx  = w0 + c;
        float v = 0.f;
        if ((unsigned)gy < (unsigned)HH && (unsigned)gx < (unsigned)WW)
            v = in[(size_t)ic * HW + gy * WW + gx];
        tile[idx] = v;
    }
    __syncthreads();

    const int oc0 = blockIdx.z * 8;
    const float* wch = wt + (size_t)blockIdx.z * 288 * 8;

    float acc[8];
    #pragma unroll
    for (int o = 0; o < 8; o++) acc[o] = bias[oc0 + o];

    const float* tp = tile + ty * 18 + tx;
    #pragma unroll 4
    for (int ic = 0; ic < CH; ic++) {
        const float* t = tp + ic * 324;
        #pragma unroll
        for (int kh = 0; kh < 3; kh++) {
            #pragma unroll
            for (int kw = 0; kw < 3; kw++) {
                const float v = t[kh * 18 + kw];
                const float* wp = wch + (ic * 9 + kh * 3 + kw) * 8;
                #pragma unroll
                for (int o = 0; o < 8; o++)
                    acc[o] = fmaf(wp[o], v, acc[o]);
            }
        }
    }

    const int hr = blockIdx.y * 16 + ty;    // row within out plane
    const int hg = row_start + hr;          // global row (for resid)
    const int x  = blockIdx.x * 16 + tx;
    #pragma unroll
    for (int o = 0; o < 8; o++) {
        const size_t oi = (size_t)(oc0 + o) * out_rows * WW + (size_t)hr * WW + x;
        float v = acc[o];
        if (RESID) v += resid[(size_t)(oc0 + o) * HW + (size_t)hg * WW + x];
        out[oi] = v;
    }
}

// ---------------------------------------------------------------------------
// DCNv2 core for one batch, one row-stripe. One thread per pixel computes all
// 32 output channels; weights via uniform global reads from wt_dcn [288][32].
// ---------------------------------------------------------------------------
__global__ __launch_bounds__(256) void dcn_kernel(
    const float* __restrict__ x,       // [32, H, W]  (batch base)
    const float* __restrict__ om,      // [216, rows, W]  (stripe-local)
    const float* __restrict__ wt_dcn,  // [288][32]
    const float* __restrict__ b_dcn,   // [32]
    float* __restrict__ fea,           // [32, H, W]  (batch base)
    int row_start, int rows)
{
    const int p = blockIdx.x * blockDim.x + threadIdx.x;
    if (p >= rows * WW) return;
    const int hr = p / WW;
    const int h  = row_start + hr;
    const int wx = p - hr * WW;
    const int pfull = h * WW + wx;
    const int srW = rows * WW;

    float acc[CH];
    #pragma unroll
    for (int o = 0; o < CH; o++) acc[o] = 0.f;

    #pragma unroll 1
    for (int g = 0; g < DGROUPS; g++) {
        #pragma unroll 1
        for (int k = 0; k < KK; k++) {
            const int ch = g * KK + k;
            const float dy = om[(size_t)ch * srW + p];
            const float dx = om[(size_t)(72 + ch) * srW + p];
            const float mm = om[(size_t)(144 + ch) * srW + p];
            const float mask = 1.f / (1.f + expf(-mm));

            const float py = dy + (float)h + (float)(k / 3 - 1);
            const float px = dx + (float)wx + (float)(k % 3 - 1);

            const float y0f = floorf(py);
            const float x0f = floorf(px);
            const int y0 = (int)y0f;
            const int x0 = (int)x0f;
            const float ly = py - y0f;
            const float lx = px - x0f;

            float w00 = (1.f - ly) * (1.f - lx);
            float w01 = (1.f - ly) * lx;
            float w10 = ly * (1.f - lx);
            float w11 = ly * lx;

            const bool vy0 = (y0     >= 0) && (y0     < HH);
            const bool vy1 = (y0 + 1 >= 0) && (y0 + 1 < HH);
            const bool vx0 = (x0     >= 0) && (x0     < WW);
            const bool vx1 = (x0 + 1 >= 0) && (x0 + 1 < WW);
            if (!(vy0 && vx0)) w00 = 0.f;
            if (!(vy0 && vx1)) w01 = 0.f;
            if (!(vy1 && vx0)) w10 = 0.f;
            if (!(vy1 && vx1)) w11 = 0.f;

            const int cy0 = min(max(y0,     0), HH - 1);
            const int cy1 = min(max(y0 + 1, 0), HH - 1);
            const int cx0 = min(max(x0,     0), WW - 1);
            const int cx1 = min(max(x0 + 1, 0), WW - 1);
            const int i00 = cy0 * WW + cx0;
            const int i01 = cy0 * WW + cx1;
            const int i10 = cy1 * WW + cx0;
            const int i11 = cy1 * WW + cx1;

            #pragma unroll
            for (int c = 0; c < CPG; c++) {
                const float* xc = x + (size_t)(g * CPG + c) * HW;
                const float v = w00 * xc[i00] + w01 * xc[i01] +
                                w10 * xc[i10] + w11 * xc[i11];
                const float mv = mask * v;
                const float* wrow = wt_dcn + (size_t)((g * CPG + c) * 9 + k) * CH;
                #pragma unroll
                for (int o = 0; o < CH; o++)
                    acc[o] = fmaf(wrow[o], mv, acc[o]);
            }
        }
    }

    #pragma unroll
    for (int o = 0; o < CH; o++) {
        float v = acc[o] + b_dcn[o];
        v = (v > 0.f) ? v : NEG_SLOPE * v;
        fea[(size_t)o * HW + pfull] = v;
    }
}

extern "C" void kernel_launch(void* const* d_in, const int* in_sizes, int n_in,
                              void* d_out, int out_size, void* d_ws, size_t ws_size,
                              hipStream_t stream) {
    const float* x      = (const float*)d_in[0];
    const float* offset = (const float*)d_in[1];
    const float* w_off  = (const float*)d_in[2];
    const float* b_off  = (const float*)d_in[3];
    const float* w_dcn  = (const float*)d_in[4];
    const float* b_dcn  = (const float*)d_in[5];
    const float* w_c1   = (const float*)d_in[6];
    const float* b_c1   = (const float*)d_in[7];
    float* out = (float*)d_out;

    // ws carve-up
    char* wsp = (char*)d_ws;
    float* fea = (float*)wsp;                 wsp += (size_t)BB * CH * HW * sizeof(float);
    float* wt_off = (float*)wsp;              wsp += WOFF_N * sizeof(float);
    float* wt_c1 = (float*)wsp;               wsp += WC1_N * sizeof(float);
    float* wt_dcn = (float*)wsp;              wsp += WDCN_N * sizeof(float);
    float* om = (float*)wsp;
    const size_t used = (size_t)(wsp - (char*)d_ws);

    const size_t row_bytes = (size_t)OMC * WW * sizeof(float);  // 221184
    const size_t avail = (ws_size > used) ? (ws_size - used) : 0;
    int rows_per = (int)(avail / row_bytes) & ~15;   // multiple of 16
    if (rows_per < 16)  rows_per = 16;   // requires ws >= ~21 MB
    if (rows_per > HH)  rows_per = HH;

    // 0) weight repack
    const int tw_n = WOFF_N + WC1_N + WDCN_N;  // 80640
    transpose_weights<<<dim3((tw_n + 255) / 256), dim3(256), 0, stream>>>(
        w_off, w_c1, w_dcn, wt_off, wt_c1, wt_dcn);

    // 1+2) per batch, per row-stripe: conv_off -> om, dcn -> fea
    for (int b = 0; b < BB; b++) {
        const float* xb   = x      + (size_t)b * CH * HW;
        const float* offb = offset + (size_t)b * CH * HW;
        float*       feab = fea    + (size_t)b * CH * HW;

        for (int r0 = 0; r0 < HH; r0 += rows_per) {
            const int rows = (r0 + rows_per <= HH) ? rows_per : (HH - r0);
            const dim3 goff(WW / 16, rows / 16, OMC / 8);
            conv3x3_tiled<false><<<goff, dim3(256), 0, stream>>>(
                offb, wt_off, b_off, nullptr, om, r0, rows);
            const dim3 gdcn((rows * WW) / 256);
            dcn_kernel<<<gdcn, dim3(256), 0, stream>>>(
                xb, om, wt_dcn, b_dcn, feab, r0, rows);
        }
    }

    // 3) conv c1 + residual
    for (int b = 0; b < BB; b++) {
        const float* feab = fea + (size_t)b * CH * HW;
        const float* xb   = x   + (size_t)b * CH * HW;
        float*       outb = out + (size_t)b * CH * HW;
        const dim3 gc1(WW / 16, HH / 16, CH / 8);
        conv3x3_tiled<true><<<gc1, dim3(256), 0, stream>>>(
            feab, wt_c1, b_c1, xb, outb, 0, HH);
    }
}

// Round 6
// 460.131 us; speedup vs baseline: 1.9931x; 1.9931x over previous
//
#include <hip/hip_runtime.h>
#include <cstddef>
#include <cstdint>

// RSABlock: conv_offset_mask (3x3) -> DCNv2 -> leaky_relu -> conv3x3 -> +x.
// B=2, C=32, H=W=256, DG=8, K=9, om channels = 216.
//
// Round 6: bf16 MFMA for both dense convs; packed [px][32ch] bf16 activations
// for MFMA B-operands and for dcn's bilinear gathers.
//   pack_px   : x,offset fp32 [32][HW] -> bf16 [HW][32] (coalesced both sides)
//   pack_w    : w_off -> [9][16mt][16r][32ic] bf16 (M pad 216->256),
//               w_c1 -> [9][2][16][32] bf16, w_dcn -> [288][32] f32
//   conv_off_mfma: 64-px tile (4 rows x 16 cols), LDS halo records at 80B
//               stride (16B-aligned ds_read_b128, banks spread), 4 waves x
//               4mt x 4nt MFMA 16x16x32_bf16. +bias -> om f32 [216][rows][256]
//   dcn_kernel: per-pixel; 8B corner gathers from packed x; fp32 contraction;
//               +bias, leaky-relu -> feapk bf16 [HW][32]
//   conv_c1_mfma: 128-px tile, M=32, fused bias + residual -> out f32.

#define CH 32
#define HH 256
#define WW 256
#define BB 2
#define HW (HH * WW)
#define OMC 216
#define NEG_SLOPE 0.2f

typedef __attribute__((ext_vector_type(8))) short short8;
typedef __attribute__((ext_vector_type(4))) float f32x4;
typedef __attribute__((ext_vector_type(4))) unsigned int u32x4;
typedef __attribute__((ext_vector_type(2))) unsigned int u32x2;

#define WPK_OFF_N (9 * 16 * 16 * 32)  // 73728
#define WPK_C1_N  (9 * 2 * 16 * 32)   // 9216
#define WTDCN_N   (288 * 32)          // 9216

__device__ __forceinline__ uint16_t f2bf(float f) {  // RNE fp32->bf16
    union { float f; uint32_t u; } x; x.f = f;
    const uint32_t r = x.u + 0x7fffu + ((x.u >> 16) & 1u);
    return (uint16_t)(r >> 16);
}
__device__ __forceinline__ float bf2f(uint32_t h) {  // low 16 bits -> fp32
    union { uint32_t u; float f; } x; x.u = h << 16; return x.f;
}

// ---------------------------------------------------------------------------
// pack_px: [32][HW] f32 -> [HW][32] bf16. blockIdx.y: 0,1 = x b0,b1; 2,3 = off.
// Loads coalesced per channel plane; each thread writes one 64B record.
// ---------------------------------------------------------------------------
__global__ __launch_bounds__(256) void pack_px(
    const float* __restrict__ x, const float* __restrict__ off,
    uint16_t* __restrict__ xpk, uint16_t* __restrict__ offpk)
{
    const int z = blockIdx.y;
    const float* src = (z < 2) ? (x + (size_t)z * CH * HW)
                               : (off + (size_t)(z - 2) * CH * HW);
    uint16_t* dst = (z < 2) ? (xpk + (size_t)z * HW * CH)
                            : (offpk + (size_t)(z - 2) * HW * CH);
    const int px = blockIdx.x * 256 + threadIdx.x;
    uint32_t w[16];
    #pragma unroll
    for (int c = 0; c < CH; c += 2) {
        const float a = src[(size_t)c * HW + px];
        const float b = src[(size_t)(c + 1) * HW + px];
        w[c >> 1] = (uint32_t)f2bf(a) | ((uint32_t)f2bf(b) << 16);
    }
    u32x4* d = (u32x4*)(dst + (size_t)px * CH);
    #pragma unroll
    for (int i = 0; i < 4; i++) {
        u32x4 v = { w[4 * i], w[4 * i + 1], w[4 * i + 2], w[4 * i + 3] };
        d[i] = v;
    }
}

// ---------------------------------------------------------------------------
// pack_w: weight repacks (see header). Inputs OIHW, t = kh*3+kw.
// ---------------------------------------------------------------------------
__global__ __launch_bounds__(256) void pack_w(
    const float* __restrict__ w_off, const float* __restrict__ w_c1,
    const float* __restrict__ w_dcn,
    uint16_t* __restrict__ wpk_off, uint16_t* __restrict__ wpk_c1,
    float* __restrict__ wt_dcn)
{
    const int i = blockIdx.x * 256 + threadIdx.x;
    if (i < WPK_OFF_N) {
        const int ic = i & 31, r = (i >> 5) & 15, mt = (i >> 9) & 15, t = i >> 13;
        const int oc = mt * 16 + r;
        const float v = (oc < OMC) ? w_off[((size_t)oc * CH + ic) * 9 + t] : 0.f;
        wpk_off[i] = f2bf(v);
    } else if (i < WPK_OFF_N + WPK_C1_N) {
        const int j = i - WPK_OFF_N;
        const int ic = j & 31, r = (j >> 5) & 15, mt = (j >> 9) & 1, t = j >> 10;
        const int oc = mt * 16 + r;
        wpk_c1[j] = f2bf(w_c1[((size_t)oc * CH + ic) * 9 + t]);
    } else if (i < WPK_OFF_N + WPK_C1_N + WTDCN_N) {
        const int j = i - (WPK_OFF_N + WPK_C1_N);
        const int o = j & 31, row = j >> 5;          // row = ic*9 + k
        wt_dcn[j] = w_dcn[(size_t)o * 288 + row];
    }
}

// ---------------------------------------------------------------------------
// conv_off_mfma: block = 4 rows x 16 cols output, all 256 (padded) oc.
// LDS halo: 6x18 pixel-records, 80B stride (64B data + pad).
// ---------------------------------------------------------------------------
__global__ __launch_bounds__(256) void conv_off_mfma(
    const uint16_t* __restrict__ inpk,  // [HW][32] bf16 (offset, batch base)
    const uint16_t* __restrict__ wpk,   // [9][16][16][32] bf16
    const float* __restrict__ bias,     // [216]
    float* __restrict__ om,             // [216][rows][256] f32
    int r0, int rows)
{
    __shared__ __align__(16) uint16_t tile[6 * 18 * 40];  // 8640 B

    const int gy0 = r0 + blockIdx.y * 4 - 1;
    const int gx0 = blockIdx.x * 16 - 1;
    for (int chunk = threadIdx.x; chunk < 6 * 18 * 4; chunk += 256) {
        const int rec = chunk >> 2, part = chunk & 3;
        const int rr = rec / 18, rc = rec - rr * 18;
        const int gy = gy0 + rr, gx = gx0 + rc;
        u32x4 v = {0u, 0u, 0u, 0u};
        if ((unsigned)gy < (unsigned)HH && (unsigned)gx < (unsigned)WW)
            v = *(const u32x4*)(inpk + ((size_t)gy * WW + gx) * CH + part * 8);
        *(u32x4*)((char*)tile + rec * 80 + part * 16) = v;
    }
    __syncthreads();

    const int lane = threadIdx.x & 63;
    const int wave = threadIdx.x >> 6;   // 0..3, owns m-tiles 4w..4w+3
    const int tx = lane & 15;
    const int q  = lane >> 4;

    f32x4 acc[4][4];
    #pragma unroll
    for (int m = 0; m < 4; m++)
        #pragma unroll
        for (int n = 0; n < 4; n++) acc[m][n] = (f32x4){0.f, 0.f, 0.f, 0.f};

    #pragma unroll
    for (int t = 0; t < 9; t++) {
        const int kh = t / 3, kw = t - kh * 3;
        short8 bfr[4], afr[4];
        #pragma unroll
        for (int n = 0; n < 4; n++)
            bfr[n] = *(const short8*)((const char*)tile +
                       ((n + kh) * 18 + (tx + kw)) * 80 + q * 16);
        #pragma unroll
        for (int m = 0; m < 4; m++) {
            const int mt = wave * 4 + m;
            afr[m] = *(const short8*)(wpk +
                       (((size_t)t * 16 + mt) * 16 + tx) * 32 + q * 8);
        }
        #pragma unroll
        for (int m = 0; m < 4; m++)
            #pragma unroll
            for (int n = 0; n < 4; n++)
                acc[m][n] = __builtin_amdgcn_mfma_f32_16x16x32_bf16(
                    afr[m], bfr[n], acc[m][n], 0, 0, 0);
    }

    const int srW = rows * WW;
    const int gx = blockIdx.x * 16 + tx;
    #pragma unroll
    for (int m = 0; m < 4; m++) {
        const int mt = wave * 4 + m;
        #pragma unroll
        for (int n = 0; n < 4; n++) {
            const int hr = blockIdx.y * 4 + n;
            #pragma unroll
            for (int i = 0; i < 4; i++) {
                const int oc = mt * 16 + q * 4 + i;
                if (oc < OMC)
                    om[(size_t)oc * srW + hr * WW + gx] = acc[m][n][i] + bias[oc];
            }
        }
    }
}

// ---------------------------------------------------------------------------
// conv_c1_mfma: block = 8 rows x 16 cols, M=32 (2 m-tiles). Fused bias+resid.
// ---------------------------------------------------------------------------
__global__ __launch_bounds__(256) void conv_c1_mfma(
    const uint16_t* __restrict__ feapk, // [HW][32] bf16 batch base
    const uint16_t* __restrict__ wpk,   // [9][2][16][32] bf16
    const float* __restrict__ bias,     // [32]
    const float* __restrict__ resid,    // [32][HW] f32 batch base (x)
    float* __restrict__ out)            // [32][HW] f32 batch base
{
    __shared__ __align__(16) uint16_t tile[10 * 18 * 40];  // 14400 B

    const int gy0 = blockIdx.y * 8 - 1;
    const int gx0 = blockIdx.x * 16 - 1;
    for (int chunk = threadIdx.x; chunk < 10 * 18 * 4; chunk += 256) {
        const int rec = chunk >> 2, part = chunk & 3;
        const int rr = rec / 18, rc = rec - rr * 18;
        const int gy = gy0 + rr, gx = gx0 + rc;
        u32x4 v = {0u, 0u, 0u, 0u};
        if ((unsigned)gy < (unsigned)HH && (unsigned)gx < (unsigned)WW)
            v = *(const u32x4*)(feapk + ((size_t)gy * WW + gx) * CH + part * 8);
        *(u32x4*)((char*)tile + rec * 80 + part * 16) = v;
    }
    __syncthreads();

    const int lane = threadIdx.x & 63;
    const int wave = threadIdx.x >> 6;
    const int tx = lane & 15;
    const int q  = lane >> 4;
    const int mt = wave & 1;
    const int nb = (wave >> 1) * 4;      // row-tile base: 0 or 4

    f32x4 acc[4];
    #pragma unroll
    for (int n = 0; n < 4; n++) acc[n] = (f32x4){0.f, 0.f, 0.f, 0.f};

    #pragma unroll
    for (int t = 0; t < 9; t++) {
        const int kh = t / 3, kw = t - kh * 3;
        const short8 afr = *(const short8*)(wpk +
                             (((size_t)t * 2 + mt) * 16 + tx) * 32 + q * 8);
        #pragma unroll
        for (int n = 0; n < 4; n++) {
            const short8 bfr = *(const short8*)((const char*)tile +
                                 ((nb + n + kh) * 18 + (tx + kw)) * 80 + q * 16);
            acc[n] = __builtin_amdgcn_mfma_f32_16x16x32_bf16(
                afr, bfr, acc[n], 0, 0, 0);
        }
    }

    const int gx = blockIdx.x * 16 + tx;
    #pragma unroll
    for (int n = 0; n < 4; n++) {
        const int gy = blockIdx.y * 8 + nb + n;
        #pragma unroll
        for (int i = 0; i < 4; i++) {
            const int oc = mt * 16 + q * 4 + i;
            const size_t idx = (size_t)oc * HW + (size_t)gy * WW + gx;
            out[idx] = acc[n][i] + bias[oc] + resid[idx];
        }
    }
}

// ---------------------------------------------------------------------------
// dcn_kernel: one block per image row (256 threads = 256 cols).
// ---------------------------------------------------------------------------
__global__ __launch_bounds__(256) void dcn_kernel(
    const uint16_t* __restrict__ xpk,   // [HW][32] bf16 batch base
    const float* __restrict__ om,       // [216][rows][256] f32
    const float* __restrict__ wt,       // [288][32] f32, row = ic*9+k
    const float* __restrict__ b_dcn,    // [32]
    uint16_t* __restrict__ feapk,       // [HW][32] bf16 batch base
    int r0, int rows)
{
    const int p  = blockIdx.x * 256 + threadIdx.x;  // stripe-local pixel
    const int hr = p >> 8;
    const int wx = p & 255;
    const int h  = r0 + hr;
    const int srW = rows * WW;

    float acc[CH];
    #pragma unroll
    for (int o = 0; o < CH; o++) acc[o] = 0.f;

    #pragma unroll 1
    for (int g = 0; g < 8; g++) {
        #pragma unroll 1
        for (int k = 0; k < 9; k++) {
            const int ch = g * 9 + k;
            const float dy = om[(size_t)ch * srW + p];
            const float dx = om[(size_t)(72 + ch) * srW + p];
            const float mm = om[(size_t)(144 + ch) * srW + p];
            const float mask = 1.f / (1.f + expf(-mm));

            const float py = dy + (float)(h + k / 3 - 1);
            const float px = dx + (float)(wx + k % 3 - 1);
            const float y0f = floorf(py), x0f = floorf(px);
            const int y0 = (int)y0f, x0 = (int)x0f;
            const float ly = py - y0f, lx = px - x0f;

            float w00 = (1.f - ly) * (1.f - lx), w01 = (1.f - ly) * lx;
            float w10 = ly * (1.f - lx),         w11 = ly * lx;
            if (!((unsigned)y0       < (unsigned)HH && (unsigned)x0       < (unsigned)WW)) w00 = 0.f;
            if (!((unsigned)y0       < (unsigned)HH && (unsigned)(x0 + 1) < (unsigned)WW)) w01 = 0.f;
            if (!((unsigned)(y0 + 1) < (unsigned)HH && (unsigned)x0       < (unsigned)WW)) w10 = 0.f;
            if (!((unsigned)(y0 + 1) < (unsigned)HH && (unsigned)(x0 + 1) < (unsigned)WW)) w11 = 0.f;
            w00 *= mask; w01 *= mask; w10 *= mask; w11 *= mask;

            const int cy0 = min(max(y0, 0), HH - 1), cy1 = min(max(y0 + 1, 0), HH - 1);
            const int cx0 = min(max(x0, 0), WW - 1), cx1 = min(max(x0 + 1, 0), WW - 1);

            const u32x2 v00 = *(const u32x2*)(xpk + ((size_t)cy0 * WW + cx0) * CH + g * 4);
            const u32x2 v01 = *(const u32x2*)(xpk + ((size_t)cy0 * WW + cx1) * CH + g * 4);
            const u32x2 v10 = *(const u32x2*)(xpk + ((size_t)cy1 * WW + cx0) * CH + g * 4);
            const u32x2 v11 = *(const u32x2*)(xpk + ((size_t)cy1 * WW + cx1) * CH + g * 4);

            #pragma unroll
            for (int c = 0; c < 4; c++) {
                const int sh = (c & 1) * 16;
                const int wi = c >> 1;
                const float f00 = bf2f((v00[wi] >> sh) & 0xffffu);
                const float f01 = bf2f((v01[wi] >> sh) & 0xffffu);
                const float f10 = bf2f((v10[wi] >> sh) & 0xffffu);
                const float f11 = bf2f((v11[wi] >> sh) & 0xffffu);
                const float v = w00 * f00 + w01 * f01 + w10 * f10 + w11 * f11;
                const float* wrow = wt + (size_t)((g * 4 + c) * 9 + k) * CH;
                #pragma unroll
                for (int o = 0; o < CH; o++)
                    acc[o] = fmaf(wrow[o], v, acc[o]);
            }
        }
    }

    uint32_t wout[16];
    #pragma unroll
    for (int o = 0; o < CH; o += 2) {
        float v0 = acc[o] + b_dcn[o];         v0 = v0 > 0.f ? v0 : NEG_SLOPE * v0;
        float v1 = acc[o + 1] + b_dcn[o + 1]; v1 = v1 > 0.f ? v1 : NEG_SLOPE * v1;
        wout[o >> 1] = (uint32_t)f2bf(v0) | ((uint32_t)f2bf(v1) << 16);
    }
    u32x4* d = (u32x4*)(feapk + ((size_t)h * WW + wx) * CH);
    #pragma unroll
    for (int i = 0; i < 4; i++) {
        u32x4 v = { wout[4 * i], wout[4 * i + 1], wout[4 * i + 2], wout[4 * i + 3] };
        d[i] = v;
    }
}

extern "C" void kernel_launch(void* const* d_in, const int* in_sizes, int n_in,
                              void* d_out, int out_size, void* d_ws, size_t ws_size,
                              hipStream_t stream) {
    const float* x      = (const float*)d_in[0];
    const float* offset = (const float*)d_in[1];
    const float* w_off  = (const float*)d_in[2];
    const float* b_off  = (const float*)d_in[3];
    const float* w_dcn  = (const float*)d_in[4];
    const float* b_dcn  = (const float*)d_in[5];
    const float* w_c1   = (const float*)d_in[6];
    const float* b_c1   = (const float*)d_in[7];
    float* out = (float*)d_out;

    auto aup = [](size_t v) { return (v + 255) & ~(size_t)255; };
    char* wsp = (char*)d_ws;
    uint16_t* xpk    = (uint16_t*)wsp; wsp += aup((size_t)BB * HW * CH * 2);
    uint16_t* offpk  = (uint16_t*)wsp; wsp += aup((size_t)BB * HW * CH * 2);
    uint16_t* feapk  = (uint16_t*)wsp; wsp += aup((size_t)BB * HW * CH * 2);
    uint16_t* wpkoff = (uint16_t*)wsp; wsp += aup((size_t)WPK_OFF_N * 2);
    uint16_t* wpkc1  = (uint16_t*)wsp; wsp += aup((size_t)WPK_C1_N * 2);
    float*    wtdcn  = (float*)wsp;    wsp += aup((size_t)WTDCN_N * 4);
    float*    om     = (float*)wsp;
    const size_t used = (size_t)(wsp - (char*)d_ws);

    const size_t row_bytes = (size_t)OMC * WW * sizeof(float);  // 221184
    const size_t avail = (ws_size > used) ? (ws_size - used) : 0;
    int rows_per = (int)(avail / row_bytes) & ~3;   // multiple of 4
    if (rows_per < 4)  rows_per = 4;    // requires ws >= ~26.5 MB
    if (rows_per > HH) rows_per = HH;

    // 0) packs
    pack_px<<<dim3(HW / 256, 4), dim3(256), 0, stream>>>(x, offset, xpk, offpk);
    const int wn = WPK_OFF_N + WPK_C1_N + WTDCN_N;
    pack_w<<<dim3((wn + 255) / 256), dim3(256), 0, stream>>>(
        w_off, w_c1, w_dcn, wpkoff, wpkc1, wtdcn);

    // 1+2) per batch, per row-stripe: conv_off (MFMA) -> om, dcn -> feapk
    for (int b = 0; b < BB; b++) {
        const uint16_t* offb = offpk + (size_t)b * HW * CH;
        const uint16_t* xb   = xpk   + (size_t)b * HW * CH;
        uint16_t*       feab = feapk + (size_t)b * HW * CH;
        for (int r0 = 0; r0 < HH; r0 += rows_per) {
            const int rows = (r0 + rows_per <= HH) ? rows_per : (HH - r0);
            conv_off_mfma<<<dim3(WW / 16, rows / 4), dim3(256), 0, stream>>>(
                offb, wpkoff, b_off, om, r0, rows);
            dcn_kernel<<<dim3(rows), dim3(256), 0, stream>>>(
                xb, om, wtdcn, b_dcn, feab, r0, rows);
        }
    }

    // 3) conv c1 (MFMA) + bias + residual
    for (int b = 0; b < BB; b++) {
        conv_c1_mfma<<<dim3(WW / 16, HH / 8), dim3(256), 0, stream>>>(
            feapk + (size_t)b * HW * CH, wpkc1, b_c1,
            x + (size_t)b * CH * HW, out + (size_t)b * CH * HW);
    }
}

// Round 7
// 379.250 us; speedup vs baseline: 2.4181x; 1.2133x over previous
//
#include <hip/hip_runtime.h>
#include <cstddef>
#include <cstdint>

// RSABlock: conv_offset_mask (3x3) -> DCNv2 -> leaky_relu -> conv3x3 -> +x.
// B=2, C=32, H=W=256, DG=8, K=9, om channels = 216.
//
// Round 7: dcn parallelized 4x — 4 sub-threads per pixel (2 groups each),
// shfl_xor reduction; grid rows*4 blocks -> ~50% occupancy (was 11%).
// Dense convs stay bf16-MFMA (round 6 structure).

#define CH 32
#define HH 256
#define WW 256
#define BB 2
#define HW (HH * WW)
#define OMC 216
#define NEG_SLOPE 0.2f

typedef __attribute__((ext_vector_type(8))) short short8;
typedef __attribute__((ext_vector_type(4))) float f32x4;
typedef __attribute__((ext_vector_type(4))) unsigned int u32x4;
typedef __attribute__((ext_vector_type(2))) unsigned int u32x2;

#define WPK_OFF_N (9 * 16 * 16 * 32)  // 73728
#define WPK_C1_N  (9 * 2 * 16 * 32)   // 9216
#define WTDCN_N   (288 * 32)          // 9216

__device__ __forceinline__ uint16_t f2bf(float f) {  // RNE fp32->bf16
    union { float f; uint32_t u; } x; x.f = f;
    const uint32_t r = x.u + 0x7fffu + ((x.u >> 16) & 1u);
    return (uint16_t)(r >> 16);
}
__device__ __forceinline__ float bf2f(uint32_t h) {  // low 16 bits -> fp32
    union { uint32_t u; float f; } x; x.u = h << 16; return x.f;
}

// ---------------------------------------------------------------------------
// pack_px: [32][HW] f32 -> [HW][32] bf16. blockIdx.y: 0,1 = x b0,b1; 2,3 = off.
// ---------------------------------------------------------------------------
__global__ __launch_bounds__(256) void pack_px(
    const float* __restrict__ x, const float* __restrict__ off,
    uint16_t* __restrict__ xpk, uint16_t* __restrict__ offpk)
{
    const int z = blockIdx.y;
    const float* src = (z < 2) ? (x + (size_t)z * CH * HW)
                               : (off + (size_t)(z - 2) * CH * HW);
    uint16_t* dst = (z < 2) ? (xpk + (size_t)z * HW * CH)
                            : (offpk + (size_t)(z - 2) * HW * CH);
    const int px = blockIdx.x * 256 + threadIdx.x;
    uint32_t w[16];
    #pragma unroll
    for (int c = 0; c < CH; c += 2) {
        const float a = src[(size_t)c * HW + px];
        const float b = src[(size_t)(c + 1) * HW + px];
        w[c >> 1] = (uint32_t)f2bf(a) | ((uint32_t)f2bf(b) << 16);
    }
    u32x4* d = (u32x4*)(dst + (size_t)px * CH);
    #pragma unroll
    for (int i = 0; i < 4; i++) {
        u32x4 v = { w[4 * i], w[4 * i + 1], w[4 * i + 2], w[4 * i + 3] };
        d[i] = v;
    }
}

// ---------------------------------------------------------------------------
// pack_w: weight repacks. Inputs OIHW, t = kh*3+kw.
// ---------------------------------------------------------------------------
__global__ __launch_bounds__(256) void pack_w(
    const float* __restrict__ w_off, const float* __restrict__ w_c1,
    const float* __restrict__ w_dcn,
    uint16_t* __restrict__ wpk_off, uint16_t* __restrict__ wpk_c1,
    float* __restrict__ wt_dcn)
{
    const int i = blockIdx.x * 256 + threadIdx.x;
    if (i < WPK_OFF_N) {
        const int ic = i & 31, r = (i >> 5) & 15, mt = (i >> 9) & 15, t = i >> 13;
        const int oc = mt * 16 + r;
        const float v = (oc < OMC) ? w_off[((size_t)oc * CH + ic) * 9 + t] : 0.f;
        wpk_off[i] = f2bf(v);
    } else if (i < WPK_OFF_N + WPK_C1_N) {
        const int j = i - WPK_OFF_N;
        const int ic = j & 31, r = (j >> 5) & 15, mt = (j >> 9) & 1, t = j >> 10;
        const int oc = mt * 16 + r;
        wpk_c1[j] = f2bf(w_c1[((size_t)oc * CH + ic) * 9 + t]);
    } else if (i < WPK_OFF_N + WPK_C1_N + WTDCN_N) {
        const int j = i - (WPK_OFF_N + WPK_C1_N);
        const int o = j & 31, row = j >> 5;          // row = ic*9 + k
        wt_dcn[j] = w_dcn[(size_t)o * 288 + row];
    }
}

// ---------------------------------------------------------------------------
// conv_off_mfma: block = 4 rows x 16 cols output, all 256 (padded) oc.
// ---------------------------------------------------------------------------
__global__ __launch_bounds__(256) void conv_off_mfma(
    const uint16_t* __restrict__ inpk,  // [HW][32] bf16 (offset, batch base)
    const uint16_t* __restrict__ wpk,   // [9][16][16][32] bf16
    const float* __restrict__ bias,     // [216]
    float* __restrict__ om,             // [216][rows][256] f32
    int r0, int rows)
{
    __shared__ __align__(16) uint16_t tile[6 * 18 * 40];  // 8640 B

    const int gy0 = r0 + blockIdx.y * 4 - 1;
    const int gx0 = blockIdx.x * 16 - 1;
    for (int chunk = threadIdx.x; chunk < 6 * 18 * 4; chunk += 256) {
        const int rec = chunk >> 2, part = chunk & 3;
        const int rr = rec / 18, rc = rec - rr * 18;
        const int gy = gy0 + rr, gx = gx0 + rc;
        u32x4 v = {0u, 0u, 0u, 0u};
        if ((unsigned)gy < (unsigned)HH && (unsigned)gx < (unsigned)WW)
            v = *(const u32x4*)(inpk + ((size_t)gy * WW + gx) * CH + part * 8);
        *(u32x4*)((char*)tile + rec * 80 + part * 16) = v;
    }
    __syncthreads();

    const int lane = threadIdx.x & 63;
    const int wave = threadIdx.x >> 6;
    const int tx = lane & 15;
    const int q  = lane >> 4;

    f32x4 acc[4][4];
    #pragma unroll
    for (int m = 0; m < 4; m++)
        #pragma unroll
        for (int n = 0; n < 4; n++) acc[m][n] = (f32x4){0.f, 0.f, 0.f, 0.f};

    #pragma unroll
    for (int t = 0; t < 9; t++) {
        const int kh = t / 3, kw = t - kh * 3;
        short8 bfr[4], afr[4];
        #pragma unroll
        for (int n = 0; n < 4; n++)
            bfr[n] = *(const short8*)((const char*)tile +
                       ((n + kh) * 18 + (tx + kw)) * 80 + q * 16);
        #pragma unroll
        for (int m = 0; m < 4; m++) {
            const int mt = wave * 4 + m;
            afr[m] = *(const short8*)(wpk +
                       (((size_t)t * 16 + mt) * 16 + tx) * 32 + q * 8);
        }
        #pragma unroll
        for (int m = 0; m < 4; m++)
            #pragma unroll
            for (int n = 0; n < 4; n++)
                acc[m][n] = __builtin_amdgcn_mfma_f32_16x16x32_bf16(
                    afr[m], bfr[n], acc[m][n], 0, 0, 0);
    }

    const int srW = rows * WW;
    const int gx = blockIdx.x * 16 + tx;
    #pragma unroll
    for (int m = 0; m < 4; m++) {
        const int mt = wave * 4 + m;
        #pragma unroll
        for (int n = 0; n < 4; n++) {
            const int hr = blockIdx.y * 4 + n;
            #pragma unroll
            for (int i = 0; i < 4; i++) {
                const int oc = mt * 16 + q * 4 + i;
                if (oc < OMC)
                    om[(size_t)oc * srW + hr * WW + gx] = acc[m][n][i] + bias[oc];
            }
        }
    }
}

// ---------------------------------------------------------------------------
// conv_c1_mfma: block = 8 rows x 16 cols, M=32 (2 m-tiles). Fused bias+resid.
// ---------------------------------------------------------------------------
__global__ __launch_bounds__(256) void conv_c1_mfma(
    const uint16_t* __restrict__ feapk, // [HW][32] bf16 batch base
    const uint16_t* __restrict__ wpk,   // [9][2][16][32] bf16
    const float* __restrict__ bias,     // [32]
    const float* __restrict__ resid,    // [32][HW] f32 batch base (x)
    float* __restrict__ out)            // [32][HW] f32 batch base
{
    __shared__ __align__(16) uint16_t tile[10 * 18 * 40];  // 14400 B

    const int gy0 = blockIdx.y * 8 - 1;
    const int gx0 = blockIdx.x * 16 - 1;
    for (int chunk = threadIdx.x; chunk < 10 * 18 * 4; chunk += 256) {
        const int rec = chunk >> 2, part = chunk & 3;
        const int rr = rec / 18, rc = rec - rr * 18;
        const int gy = gy0 + rr, gx = gx0 + rc;
        u32x4 v = {0u, 0u, 0u, 0u};
        if ((unsigned)gy < (unsigned)HH && (unsigned)gx < (unsigned)WW)
            v = *(const u32x4*)(feapk + ((size_t)gy * WW + gx) * CH + part * 8);
        *(u32x4*)((char*)tile + rec * 80 + part * 16) = v;
    }
    __syncthreads();

    const int lane = threadIdx.x & 63;
    const int wave = threadIdx.x >> 6;
    const int tx = lane & 15;
    const int q  = lane >> 4;
    const int mt = wave & 1;
    const int nb = (wave >> 1) * 4;

    f32x4 acc[4];
    #pragma unroll
    for (int n = 0; n < 4; n++) acc[n] = (f32x4){0.f, 0.f, 0.f, 0.f};

    #pragma unroll
    for (int t = 0; t < 9; t++) {
        const int kh = t / 3, kw = t - kh * 3;
        const short8 afr = *(const short8*)(wpk +
                             (((size_t)t * 2 + mt) * 16 + tx) * 32 + q * 8);
        #pragma unroll
        for (int n = 0; n < 4; n++) {
            const short8 bfr = *(const short8*)((const char*)tile +
                                 ((nb + n + kh) * 18 + (tx + kw)) * 80 + q * 16);
            acc[n] = __builtin_amdgcn_mfma_f32_16x16x32_bf16(
                afr, bfr, acc[n], 0, 0, 0);
        }
    }

    const int gx = blockIdx.x * 16 + tx;
    #pragma unroll
    for (int n = 0; n < 4; n++) {
        const int gy = blockIdx.y * 8 + nb + n;
        #pragma unroll
        for (int i = 0; i < 4; i++) {
            const int oc = mt * 16 + q * 4 + i;
            const size_t idx = (size_t)oc * HW + (size_t)gy * WW + gx;
            out[idx] = acc[n][i] + bias[oc] + resid[idx];
        }
    }
}

// ---------------------------------------------------------------------------
// dcn_kernel v2: 4 sub-threads per pixel, each handles 2 deformable groups;
// wave = 16 px x 4 subs; acc[32] reduced via shfl_xor(16), shfl_xor(32).
// Grid: rows*4 blocks of 256 (64 px/block).
// ---------------------------------------------------------------------------
__global__ __launch_bounds__(256, 4) void dcn_kernel(
    const uint16_t* __restrict__ xpk,   // [HW][32] bf16 batch base
    const float* __restrict__ om,       // [216][rows][256] f32
    const float* __restrict__ wt,       // [288][32] f32, row = ic*9+k
    const float* __restrict__ b_dcn,    // [32]
    uint16_t* __restrict__ feapk,       // [HW][32] bf16 batch base
    int r0, int rows)
{
    const int lane = threadIdx.x & 63;
    const int wave = threadIdx.x >> 6;
    const int sub  = lane >> 4;                 // 0..3 -> groups 2sub, 2sub+1
    const int p    = blockIdx.x * 64 + (wave << 4) + (lane & 15);
    const int hr = p >> 8;
    const int wx = p & 255;
    const int h  = r0 + hr;
    const int srW = rows * WW;

    float acc[CH];
    #pragma unroll
    for (int o = 0; o < CH; o++) acc[o] = 0.f;

    #pragma unroll
    for (int gi = 0; gi < 2; gi++) {
        const int g = sub * 2 + gi;
        #pragma unroll 3
        for (int k = 0; k < 9; k++) {
            const int ch = g * 9 + k;
            const float dy = om[(size_t)ch * srW + p];
            const float dx = om[(size_t)(72 + ch) * srW + p];
            const float mm = om[(size_t)(144 + ch) * srW + p];
            const float mask = 1.f / (1.f + __expf(-mm));

            const float py = dy + (float)(h + k / 3 - 1);
            const float px = dx + (float)(wx + k % 3 - 1);
            const float y0f = floorf(py), x0f = floorf(px);
            const int y0 = (int)y0f, x0 = (int)x0f;
            const float ly = py - y0f, lx = px - x0f;

            float w00 = (1.f - ly) * (1.f - lx), w01 = (1.f - ly) * lx;
            float w10 = ly * (1.f - lx),         w11 = ly * lx;
            if (!((unsigned)y0       < (unsigned)HH && (unsigned)x0       < (unsigned)WW)) w00 = 0.f;
            if (!((unsigned)y0       < (unsigned)HH && (unsigned)(x0 + 1) < (unsigned)WW)) w01 = 0.f;
            if (!((unsigned)(y0 + 1) < (unsigned)HH && (unsigned)x0       < (unsigned)WW)) w10 = 0.f;
            if (!((unsigned)(y0 + 1) < (unsigned)HH && (unsigned)(x0 + 1) < (unsigned)WW)) w11 = 0.f;
            w00 *= mask; w01 *= mask; w10 *= mask; w11 *= mask;

            const int cy0 = min(max(y0, 0), HH - 1), cy1 = min(max(y0 + 1, 0), HH - 1);
            const int cx0 = min(max(x0, 0), WW - 1), cx1 = min(max(x0 + 1, 0), WW - 1);

            const u32x2 v00 = *(const u32x2*)(xpk + ((size_t)cy0 * WW + cx0) * CH + g * 4);
            const u32x2 v01 = *(const u32x2*)(xpk + ((size_t)cy0 * WW + cx1) * CH + g * 4);
            const u32x2 v10 = *(const u32x2*)(xpk + ((size_t)cy1 * WW + cx0) * CH + g * 4);
            const u32x2 v11 = *(const u32x2*)(xpk + ((size_t)cy1 * WW + cx1) * CH + g * 4);

            #pragma unroll
            for (int c = 0; c < 4; c++) {
                const int sh = (c & 1) * 16;
                const int wi = c >> 1;
                const float f00 = bf2f((v00[wi] >> sh) & 0xffffu);
                const float f01 = bf2f((v01[wi] >> sh) & 0xffffu);
                const float f10 = bf2f((v10[wi] >> sh) & 0xffffu);
                const float f11 = bf2f((v11[wi] >> sh) & 0xffffu);
                const float v = w00 * f00 + w01 * f01 + w10 * f10 + w11 * f11;
                const float* wrow = wt + (size_t)((g * 4 + c) * 9 + k) * CH;
                #pragma unroll
                for (int o = 0; o < CH; o++)
                    acc[o] = fmaf(wrow[o], v, acc[o]);
            }
        }
    }

    // reduce partial acc across the 4 subs (lanes ^16, ^32)
    #pragma unroll
    for (int o = 0; o < CH; o++) {
        acc[o] += __shfl_xor(acc[o], 16, 64);
        acc[o] += __shfl_xor(acc[o], 32, 64);
    }

    if (sub == 0) {
        uint32_t wout[16];
        #pragma unroll
        for (int o = 0; o < CH; o += 2) {
            float v0 = acc[o] + b_dcn[o];         v0 = v0 > 0.f ? v0 : NEG_SLOPE * v0;
            float v1 = acc[o + 1] + b_dcn[o + 1]; v1 = v1 > 0.f ? v1 : NEG_SLOPE * v1;
            wout[o >> 1] = (uint32_t)f2bf(v0) | ((uint32_t)f2bf(v1) << 16);
        }
        u32x4* d = (u32x4*)(feapk + ((size_t)h * WW + wx) * CH);
        #pragma unroll
        for (int i = 0; i < 4; i++) {
            u32x4 v = { wout[4 * i], wout[4 * i + 1], wout[4 * i + 2], wout[4 * i + 3] };
            d[i] = v;
        }
    }
}

extern "C" void kernel_launch(void* const* d_in, const int* in_sizes, int n_in,
                              void* d_out, int out_size, void* d_ws, size_t ws_size,
                              hipStream_t stream) {
    const float* x      = (const float*)d_in[0];
    const float* offset = (const float*)d_in[1];
    const float* w_off  = (const float*)d_in[2];
    const float* b_off  = (const float*)d_in[3];
    const float* w_dcn  = (const float*)d_in[4];
    const float* b_dcn  = (const float*)d_in[5];
    const float* w_c1   = (const float*)d_in[6];
    const float* b_c1   = (const float*)d_in[7];
    float* out = (float*)d_out;

    auto aup = [](size_t v) { return (v + 255) & ~(size_t)255; };
    char* wsp = (char*)d_ws;
    uint16_t* xpk    = (uint16_t*)wsp; wsp += aup((size_t)BB * HW * CH * 2);
    uint16_t* offpk  = (uint16_t*)wsp; wsp += aup((size_t)BB * HW * CH * 2);
    uint16_t* feapk  = (uint16_t*)wsp; wsp += aup((size_t)BB * HW * CH * 2);
    uint16_t* wpkoff = (uint16_t*)wsp; wsp += aup((size_t)WPK_OFF_N * 2);
    uint16_t* wpkc1  = (uint16_t*)wsp; wsp += aup((size_t)WPK_C1_N * 2);
    float*    wtdcn  = (float*)wsp;    wsp += aup((size_t)WTDCN_N * 4);
    float*    om     = (float*)wsp;
    const size_t used = (size_t)(wsp - (char*)d_ws);

    const size_t row_bytes = (size_t)OMC * WW * sizeof(float);  // 221184
    const size_t avail = (ws_size > used) ? (ws_size - used) : 0;
    int rows_per = (int)(avail / row_bytes) & ~3;   // multiple of 4
    if (rows_per < 4)  rows_per = 4;
    if (rows_per > HH) rows_per = HH;

    // 0) packs
    pack_px<<<dim3(HW / 256, 4), dim3(256), 0, stream>>>(x, offset, xpk, offpk);
    const int wn = WPK_OFF_N + WPK_C1_N + WTDCN_N;
    pack_w<<<dim3((wn + 255) / 256), dim3(256), 0, stream>>>(
        w_off, w_c1, w_dcn, wpkoff, wpkc1, wtdcn);

    // 1+2) per batch, per row-stripe: conv_off (MFMA) -> om, dcn -> feapk
    for (int b = 0; b < BB; b++) {
        const uint16_t* offb = offpk + (size_t)b * HW * CH;
        const uint16_t* xb   = xpk   + (size_t)b * HW * CH;
        uint16_t*       feab = feapk + (size_t)b * HW * CH;
        for (int r0 = 0; r0 < HH; r0 += rows_per) {
            const int rows = (r0 + rows_per <= HH) ? rows_per : (HH - r0);
            conv_off_mfma<<<dim3(WW / 16, rows / 4), dim3(256), 0, stream>>>(
                offb, wpkoff, b_off, om, r0, rows);
            dcn_kernel<<<dim3(rows * 4), dim3(256), 0, stream>>>(
                xb, om, wtdcn, b_dcn, feab, r0, rows);
        }
    }

    // 3) conv c1 (MFMA) + bias + residual
    for (int b = 0; b < BB; b++) {
        conv_c1_mfma<<<dim3(WW / 16, HH / 8), dim3(256), 0, stream>>>(
            feapk + (size_t)b * HW * CH, wpkc1, b_c1,
            x + (size_t)b * CH * HW, out + (size_t)b * CH * HW);
    }
}